// Round 4
// baseline (344.618 us; speedup 1.0000x reference)
//
#include <hip/hip_runtime.h>
#include <hip/hip_cooperative_groups.h>
#include <math.h>

namespace cg = cooperative_groups;

#define NNODES 4096
#define WPR 128          // bitmask words per row (4096 bits)
#define FDIM 512
#define CHID 64
#define NHEAD 8
#define NCLS 7
#define MAXD 4096        // neighbor-list stride (worst-case safe)

typedef short bf16x8 __attribute__((ext_vector_type(8)));
typedef float f32x4  __attribute__((ext_vector_type(4)));

// round-to-nearest-even f32 -> bf16 (finite inputs only)
static __device__ inline short f2bf(float f) {
    union { float f; unsigned u; } v; v.f = f;
    unsigned r = v.u + 0x7fffu + ((v.u >> 16) & 1u);
    return (short)(r >> 16);
}

__global__ void __launch_bounds__(256, 4)
k_fused(const float* __restrict__ x, const int* __restrict__ ei,
        const float* __restrict__ W1, const float* __restrict__ b1,
        const float* __restrict__ al1, const float* __restrict__ ar1,
        const float* __restrict__ W2, const float* __restrict__ b2,
        const float* __restrict__ al2, const float* __restrict__ ar2,
        float* __restrict__ out, int E,
        unsigned int* __restrict__ adj, short* __restrict__ Bp,
        float* __restrict__ feats1, float* __restrict__ s1,
        float* __restrict__ feats2, float* __restrict__ s2,
        int* __restrict__ nbrL, int* __restrict__ degA) {
    cg::grid_group grid = cg::this_grid();
    const int tid = threadIdx.x, bid = blockIdx.x;
    const int w = tid >> 6, l = tid & 63;
    const int gw = bid * 4 + w;              // global wave id
    const int gid = bid * 256 + tid;         // global thread id
    const int nwaves = gridDim.x * 4;
    const int gstride = gridDim.x * 256;

    // ---- P0: adjacency diagonal init (wave per row) + W1 bf16 fragment pack ----
    for (int i = gw; i < NNODES; i += nwaves) {
        const int d = i >> 5;
        const unsigned bit = 1u << (i & 31);
        adj[i * WPR + l]      = (l == d)        ? bit : 0u;
        adj[i * WPR + 64 + l] = ((64 + l) == d) ? bit : 0u;
    }
    for (int t = gid; t < 32768; t += gstride) {
        int j = t & 7, ll = (t >> 3) & 63, ww = (t >> 9) & 3, kb = t >> 11;
        Bp[t] = f2bf(W1[(kb * 32 + (ll >> 4) * 8 + j) * 64 + (ww * 16 + (ll & 15))]);
    }
    grid.sync();

    // ---- P1: scatter edges into bitmask ----
    for (int e = gid; e < E; e += gstride) {
        int r = ei[e], c = ei[E + e];
        atomicOr(&adj[r * WPR + (c >> 5)], 1u << (c & 31));
    }
    grid.sync();

    // ---- P2a: neighbor-list build (wave per node, popc + shfl prefix scan) ----
    for (int i = gw; i < NNODES; i += nwaves) {
        const unsigned w0 = adj[i * WPR + 2 * l];
        const unsigned w1 = adj[i * WPR + 2 * l + 1];
        const int c0 = __popc(w0), c1 = __popc(w1);
        const int tot = c0 + c1;
        int v = tot;
        #pragma unroll
        for (int d = 1; d < 64; d <<= 1) {
            int t = __shfl_up(v, d);
            if (l >= d) v += t;
        }
        int base = i * MAXD + (v - tot);
        unsigned bits = w0; int p = 0;
        while (bits) { int bb = __ffs(bits) - 1; bits &= bits - 1; nbrL[base + p++] = l * 64 + bb; }
        base += c0;
        bits = w1; p = 0;
        while (bits) { int bb = __ffs(bits) - 1; bits &= bits - 1; nbrL[base + p++] = l * 64 + 32 + bb; }
        if (l == 63) degA[i] = v;
    }
    // ---- P2b: layer-1 GEMM via bf16 MFMA + bias + per-node scores ----
    {
        const bf16x8* bp = (const bf16x8*)Bp;
        for (int tb = bid; tb < NNODES / 16; tb += gridDim.x) {
            const int row0 = tb * 16;
            const int arow = row0 + (l & 15);
            const int koff = (l >> 4) * 8;
            f32x4 acc = {0.f, 0.f, 0.f, 0.f};
            #pragma unroll 4
            for (int kb = 0; kb < 16; ++kb) {
                const float* ap = &x[arow * FDIM + kb * 32 + koff];
                const float4 a0 = *(const float4*)ap;
                const float4 a1 = *(const float4*)(ap + 4);
                bf16x8 af = { f2bf(a0.x), f2bf(a0.y), f2bf(a0.z), f2bf(a0.w),
                              f2bf(a1.x), f2bf(a1.y), f2bf(a1.z), f2bf(a1.w) };
                bf16x8 bfr = bp[(kb * 4 + w) * 64 + l];
                acc = __builtin_amdgcn_mfma_f32_16x16x32_bf16(af, bfr, acc, 0, 0, 0);
            }
            const int col = w * 16 + (l & 15);
            const int r0 = row0 + (l >> 4) * 4;
            const float bias = b1[col];
            const int c = col & 7, h = col >> 3;
            const float vl = al1[c * NHEAD + h];
            const float vr = ar1[c * NHEAD + h];
            #pragma unroll
            for (int r = 0; r < 4; ++r) {
                float fv = acc[r] + bias;
                feats1[(r0 + r) * CHID + col] = fv;
                float ps = fv * vl, pt = fv * vr;
                ps += __shfl_xor(ps, 1); ps += __shfl_xor(ps, 2); ps += __shfl_xor(ps, 4);
                pt += __shfl_xor(pt, 1); pt += __shfl_xor(pt, 2); pt += __shfl_xor(pt, 4);
                if ((l & 7) == 0) {
                    s1[(r0 + r) * 16 + h] = ps;
                    s1[(r0 + r) * 16 + 8 + h] = pt;
                }
            }
        }
    }
    grid.sync();

    // ---- P3: layer-1 sparse attention + ELU + fused layer-2 projection & scores ----
    {
        const int h = l >> 3;
        for (int i = gw; i < NNODES; i += nwaves) {
            const int nn = degA[i];
            const float stgt = s1[i * 16 + 8 + h];
            float den = 0.f, acc = 0.f;
            if (nn <= 64) {
                const int jv = nbrL[i * MAXD + l];
                for (int k = 0; k < nn; ++k) {
                    const int j = __shfl(jv, k);
                    float sc = s1[j * 16 + h] + stgt;
                    sc = sc > 0.f ? sc : 0.2f * sc;
                    const float p = __expf(sc);   // |scores| small: max-pass not needed
                    den += p;
                    acc = fmaf(p, feats1[j * CHID + l], acc);
                }
            } else {
                for (int k0 = 0; k0 < nn; k0 += 64) {
                    const int rem = nn - k0;
                    const int cmax = rem < 64 ? rem : 64;
                    const int jv = nbrL[i * MAXD + k0 + (l < cmax ? l : 0)];
                    for (int k = 0; k < cmax; ++k) {
                        const int j = __shfl(jv, k);
                        float sc = s1[j * 16 + h] + stgt;
                        sc = sc > 0.f ? sc : 0.2f * sc;
                        const float p = __expf(sc);
                        den += p;
                        acc = fmaf(p, feats1[j * CHID + l], acc);
                    }
                }
            }
            const float o = acc / den;
            const float h1v = o > 0.f ? o : (__expf(o) - 1.f);   // ELU
            float t7[NCLS];
            #pragma unroll
            for (int c2 = 0; c2 < NCLS; ++c2) {
                float p = h1v * W2[l * NCLS + c2];
                p += __shfl_xor(p, 1);  p += __shfl_xor(p, 2);  p += __shfl_xor(p, 4);
                p += __shfl_xor(p, 8);  p += __shfl_xor(p, 16); p += __shfl_xor(p, 32);
                t7[c2] = p + b2[c2];
            }
            if (l == 0) {
                float ss = 0.f, st = 0.f;
                #pragma unroll
                for (int c2 = 0; c2 < NCLS; ++c2) {
                    ss = fmaf(t7[c2], al2[c2], ss);
                    st = fmaf(t7[c2], ar2[c2], st);
                }
                #pragma unroll
                for (int c2 = 0; c2 < NCLS; ++c2) feats2[i * 8 + c2] = t7[c2];
                feats2[i * 8 + 7] = 0.f;
                s2[i * 2] = ss;
                s2[i * 2 + 1] = st;
            }
        }
    }
    grid.sync();

    // ---- P4: layer-2 sparse attention -> output [4096,7] f32 ----
    {
        const int c = l & 7;
        for (int i = gw; i < NNODES; i += nwaves) {
            const int nn = degA[i];
            const float stgt = s2[i * 2 + 1];
            float den = 0.f, acc = 0.f;
            if (nn <= 64) {
                const int jv = nbrL[i * MAXD + l];
                for (int k = 0; k < nn; ++k) {
                    const int j = __shfl(jv, k);
                    float sc = s2[j * 2] + stgt;
                    sc = sc > 0.f ? sc : 0.2f * sc;
                    const float p = __expf(sc);
                    den += p;
                    acc = fmaf(p, feats2[j * 8 + c], acc);
                }
            } else {
                for (int k0 = 0; k0 < nn; k0 += 64) {
                    const int rem = nn - k0;
                    const int cmax = rem < 64 ? rem : 64;
                    const int jv = nbrL[i * MAXD + k0 + (l < cmax ? l : 0)];
                    for (int k = 0; k < cmax; ++k) {
                        const int j = __shfl(jv, k);
                        float sc = s2[j * 2] + stgt;
                        sc = sc > 0.f ? sc : 0.2f * sc;
                        const float p = __expf(sc);
                        den += p;
                        acc = fmaf(p, feats2[j * 8 + c], acc);
                    }
                }
            }
            if (l < NCLS) out[i * NCLS + l] = acc / den;
        }
    }
}

extern "C" void kernel_launch(void* const* d_in, const int* in_sizes, int n_in,
                              void* d_out, int out_size, void* d_ws, size_t ws_size,
                              hipStream_t stream) {
    const float* x   = (const float*)d_in[0];
    const int*   ei  = (const int*)d_in[1];
    const float* W1  = (const float*)d_in[2];
    const float* b1  = (const float*)d_in[3];
    const float* al1 = (const float*)d_in[4];
    const float* ar1 = (const float*)d_in[5];
    const float* W2  = (const float*)d_in[6];
    const float* b2  = (const float*)d_in[7];
    const float* al2 = (const float*)d_in[8];
    const float* ar2 = (const float*)d_in[9];
    float* out = (float*)d_out;
    int E = in_sizes[1] / 2;

    char* ws = (char*)d_ws;
    unsigned int* adj = (unsigned int*)ws;                 // 2 MiB
    short* Bp     = (short*)(ws + (2u << 20));             // 64 KiB (packed bf16 W1)
    float* feats1 = (float*)(ws + (3u << 20));             // 1 MiB
    float* s1     = (float*)(ws + (4u << 20));             // 256 KiB
    float* feats2 = (float*)(ws + (5u << 20));             // 128 KiB
    float* s2     = (float*)(ws + (6u << 20));             // 32 KiB
    int*   degA   = (int*)  (ws + (7u << 20));             // 16 KiB
    int*   nbrL   = (int*)  (ws + (16u << 20));            // 64 MiB

    int nb = 0;
    hipError_t oerr = hipOccupancyMaxActiveBlocksPerMultiprocessor(&nb, k_fused, 256, 0);
    if (oerr != hipSuccess || nb < 1) nb = 1;
    if (nb > 4) nb = 4;
    dim3 gridDim(256 * nb), blockDim(256);

    void* args[] = { (void*)&x, (void*)&ei, (void*)&W1, (void*)&b1, (void*)&al1, (void*)&ar1,
                     (void*)&W2, (void*)&b2, (void*)&al2, (void*)&ar2, (void*)&out, (void*)&E,
                     (void*)&adj, (void*)&Bp, (void*)&feats1, (void*)&s1,
                     (void*)&feats2, (void*)&s2, (void*)&nbrL, (void*)&degA };
    hipLaunchCooperativeKernel((void*)k_fused, gridDim, blockDim, args, 0, stream);
}

// Round 5
// 110.516 us; speedup vs baseline: 3.1183x; 3.1183x over previous
//
#include <hip/hip_runtime.h>
#include <math.h>

#define NNODES 4096
#define WPR 128          // bitmask words per row (4096 bits)
#define FDIM 512
#define CHID 64
#define NHEAD 8
#define NCLS 7
#define MAXD 4096        // neighbor-list stride (worst-case safe)

typedef short bf16x8 __attribute__((ext_vector_type(8)));
typedef float f32x4  __attribute__((ext_vector_type(4)));

// round-to-nearest-even f32 -> bf16 (finite inputs only)
static __device__ inline short f2bf(float f) {
    union { float f; unsigned u; } v; v.f = f;
    unsigned r = v.u + 0x7fffu + ((v.u >> 16) & 1u);
    return (short)(r >> 16);
}

// ---------- K1: zero adj + deg, pack W1 into bf16 MFMA B-fragments ----------
// Bp[((kb*4 + cq)*64 + l)*8 + j] = bf16( W1[(kb*32 + (l>>4)*8 + j)*64 + (cq*16 + (l&15))] )
__global__ void k_init(unsigned int* __restrict__ adj, int* __restrict__ deg,
                       const float* __restrict__ W1, short* __restrict__ Bp) {
    const int gid = blockIdx.x * 256 + threadIdx.x;
    const int gs = gridDim.x * 256;
    for (int t = gid; t < NNODES * WPR; t += gs) adj[t] = 0u;
    for (int t = gid; t < NNODES; t += gs) deg[t] = 0;
    for (int t = gid; t < 32768; t += gs) {
        int j = t & 7, l = (t >> 3) & 63, cq = (t >> 9) & 3, kb = t >> 11;
        Bp[t] = f2bf(W1[(kb * 32 + (l >> 4) * 8 + j) * 64 + (cq * 16 + (l & 15))]);
    }
}

// ---------- K2: edge scatter with dedup-append (atomicOr old-value) + diagonal ----------
__global__ void k_scatter(const int* __restrict__ ei, int E, unsigned int* __restrict__ adj,
                          int* __restrict__ deg, int* __restrict__ nbrL) {
    const int t = blockIdx.x * 256 + threadIdx.x;
    if (t >= E + NNODES) return;
    int r, c;
    if (t < E) { r = ei[t]; c = ei[E + t]; }
    else       { r = c = t - E; }                     // self-loop / diagonal
    const unsigned bit = 1u << (c & 31);
    const unsigned old = atomicOr(&adj[r * WPR + (c >> 5)], bit);
    if (!(old & bit)) {
        const int p = atomicAdd(&deg[r], 1);
        nbrL[r * MAXD + p] = c;
    }
}

// ---------- K3: layer-1 GEMM via bf16 MFMA (split-K across 4 waves) + bias + scores ----------
// 256 blocks x 256 threads; block = 16 rows x 64 cols; wave w = K-quarter kb in [4w,4w+4)
__global__ void __launch_bounds__(256) k_gemm(const float* __restrict__ x, const short* __restrict__ Bp,
                                              const float* __restrict__ b1, const float* __restrict__ al,
                                              const float* __restrict__ ar,
                                              float* __restrict__ feats, float* __restrict__ s1) {
    __shared__ float red[4][4][64][4];   // [w][cq][l][r] = 16 KB
    const int w = threadIdx.x >> 6, l = threadIdx.x & 63;
    const int row0 = blockIdx.x * 16;
    const int arow = row0 + (l & 15);
    const int koff = (l >> 4) * 8;
    const bf16x8* bp = (const bf16x8*)Bp;
    f32x4 acc0 = {0,0,0,0}, acc1 = {0,0,0,0}, acc2 = {0,0,0,0}, acc3 = {0,0,0,0};
    #pragma unroll
    for (int q = 0; q < 4; ++q) {
        const int kb = w * 4 + q;
        const float* ap = &x[arow * FDIM + kb * 32 + koff];
        const float4 a0 = *(const float4*)ap;
        const float4 a1 = *(const float4*)(ap + 4);
        bf16x8 af = { f2bf(a0.x), f2bf(a0.y), f2bf(a0.z), f2bf(a0.w),
                      f2bf(a1.x), f2bf(a1.y), f2bf(a1.z), f2bf(a1.w) };
        acc0 = __builtin_amdgcn_mfma_f32_16x16x32_bf16(af, bp[(kb * 4 + 0) * 64 + l], acc0, 0, 0, 0);
        acc1 = __builtin_amdgcn_mfma_f32_16x16x32_bf16(af, bp[(kb * 4 + 1) * 64 + l], acc1, 0, 0, 0);
        acc2 = __builtin_amdgcn_mfma_f32_16x16x32_bf16(af, bp[(kb * 4 + 2) * 64 + l], acc2, 0, 0, 0);
        acc3 = __builtin_amdgcn_mfma_f32_16x16x32_bf16(af, bp[(kb * 4 + 3) * 64 + l], acc3, 0, 0, 0);
    }
    #pragma unroll
    for (int r = 0; r < 4; ++r) {
        red[w][0][l][r] = acc0[r];
        red[w][1][l][r] = acc1[r];
        red[w][2][l][r] = acc2[r];
        red[w][3][l][r] = acc3[r];
    }
    __syncthreads();
    // thread (w,l) finalizes col = w*16+(l&15), rows r0..r0+3
    const int col = w * 16 + (l & 15);
    const int r0 = row0 + (l >> 4) * 4;
    const float bias = b1[col];
    const int c = col & 7, h = col >> 3;
    const float vl = al[c * NHEAD + h];   // a_left1[c][h]
    const float vr = ar[c * NHEAD + h];
    #pragma unroll
    for (int r = 0; r < 4; ++r) {
        float fv = red[0][w][l][r] + red[1][w][l][r] + red[2][w][l][r] + red[3][w][l][r] + bias;
        feats[(r0 + r) * CHID + col] = fv;
        float ps = fv * vl, pt = fv * vr;
        ps += __shfl_xor(ps, 1); ps += __shfl_xor(ps, 2); ps += __shfl_xor(ps, 4);
        pt += __shfl_xor(pt, 1); pt += __shfl_xor(pt, 2); pt += __shfl_xor(pt, 4);
        if ((l & 7) == 0) {
            s1[(r0 + r) * 16 + h] = ps;
            s1[(r0 + r) * 16 + 8 + h] = pt;
        }
    }
}

// ---------- K4: layer-1 sparse attention + ELU + fused layer-2 projection & scores ----------
// 1024 blocks x 256 threads; wave w -> node i = blockIdx*4 + w; lane l = h*8+c
__global__ void __launch_bounds__(256) k_attn1(const int* __restrict__ nbrL, const int* __restrict__ deg,
                                               const float* __restrict__ feats,
                                               const float* __restrict__ s1,
                                               const float* __restrict__ W2,
                                               const float* __restrict__ b2,
                                               const float* __restrict__ al2,
                                               const float* __restrict__ ar2,
                                               float* __restrict__ feats2,
                                               float* __restrict__ s2) {
    const int w = threadIdx.x >> 6, l = threadIdx.x & 63;
    const int i = blockIdx.x * 4 + w;
    const int h = l >> 3;
    const int nn = deg[i];
    const float stgt = s1[i * 16 + 8 + h];
    float den = 0.f, acc = 0.f;
    if (nn <= 64) {
        const int jv = nbrL[i * MAXD + (l < nn ? l : 0)];
        for (int k = 0; k < nn; ++k) {
            const int j = __shfl(jv, k);
            float sc = s1[j * 16 + h] + stgt;
            sc = sc > 0.f ? sc : 0.2f * sc;
            const float p = __expf(sc);          // |scores| small: max-pass not needed
            den += p;
            acc = fmaf(p, feats[j * CHID + l], acc);
        }
    } else {
        for (int k0 = 0; k0 < nn; k0 += 64) {
            const int rem = nn - k0;
            const int cmax = rem < 64 ? rem : 64;
            const int jv = nbrL[i * MAXD + k0 + (l < cmax ? l : 0)];
            for (int k = 0; k < cmax; ++k) {
                const int j = __shfl(jv, k);
                float sc = s1[j * 16 + h] + stgt;
                sc = sc > 0.f ? sc : 0.2f * sc;
                const float p = __expf(sc);
                den += p;
                acc = fmaf(p, feats[j * CHID + l], acc);
            }
        }
    }
    const float o = acc / den;
    const float h1v = o > 0.f ? o : (__expf(o) - 1.f);   // ELU
    float t7[NCLS];
    #pragma unroll
    for (int c2 = 0; c2 < NCLS; ++c2) {
        float p = h1v * W2[l * NCLS + c2];
        p += __shfl_xor(p, 1);  p += __shfl_xor(p, 2);  p += __shfl_xor(p, 4);
        p += __shfl_xor(p, 8);  p += __shfl_xor(p, 16); p += __shfl_xor(p, 32);
        t7[c2] = p + b2[c2];
    }
    if (l == 0) {
        float ss = 0.f, st = 0.f;
        #pragma unroll
        for (int c2 = 0; c2 < NCLS; ++c2) {
            ss = fmaf(t7[c2], al2[c2], ss);
            st = fmaf(t7[c2], ar2[c2], st);
        }
        #pragma unroll
        for (int c2 = 0; c2 < NCLS; ++c2) feats2[i * 8 + c2] = t7[c2];
        feats2[i * 8 + 7] = 0.f;
        s2[i * 2] = ss;
        s2[i * 2 + 1] = st;
    }
}

// ---------- K5: layer-2 sparse attention -> output [4096,7] f32 ----------
__global__ void __launch_bounds__(256) k_attn2(const int* __restrict__ nbrL, const int* __restrict__ deg,
                                               const float* __restrict__ feats2,
                                               const float* __restrict__ s2,
                                               float* __restrict__ out) {
    const int w = threadIdx.x >> 6, l = threadIdx.x & 63;
    const int i = blockIdx.x * 4 + w;
    const int nn = deg[i];
    const int c = l & 7;
    const float stgt = s2[i * 2 + 1];
    float den = 0.f, acc = 0.f;
    if (nn <= 64) {
        const int jv = nbrL[i * MAXD + (l < nn ? l : 0)];
        for (int k = 0; k < nn; ++k) {
            const int j = __shfl(jv, k);
            float sc = s2[j * 2] + stgt;
            sc = sc > 0.f ? sc : 0.2f * sc;
            const float p = __expf(sc);
            den += p;
            acc = fmaf(p, feats2[j * 8 + c], acc);
        }
    } else {
        for (int k0 = 0; k0 < nn; k0 += 64) {
            const int rem = nn - k0;
            const int cmax = rem < 64 ? rem : 64;
            const int jv = nbrL[i * MAXD + k0 + (l < cmax ? l : 0)];
            for (int k = 0; k < cmax; ++k) {
                const int j = __shfl(jv, k);
                float sc = s2[j * 2] + stgt;
                sc = sc > 0.f ? sc : 0.2f * sc;
                const float p = __expf(sc);
                den += p;
                acc = fmaf(p, feats2[j * 8 + c], acc);
            }
        }
    }
    if (l < NCLS) out[i * NCLS + l] = acc / den;
}

extern "C" void kernel_launch(void* const* d_in, const int* in_sizes, int n_in,
                              void* d_out, int out_size, void* d_ws, size_t ws_size,
                              hipStream_t stream) {
    const float* x   = (const float*)d_in[0];
    const int*   ei  = (const int*)d_in[1];
    const float* W1  = (const float*)d_in[2];
    const float* b1  = (const float*)d_in[3];
    const float* al1 = (const float*)d_in[4];
    const float* ar1 = (const float*)d_in[5];
    const float* W2  = (const float*)d_in[6];
    const float* b2  = (const float*)d_in[7];
    const float* al2 = (const float*)d_in[8];
    const float* ar2 = (const float*)d_in[9];
    float* out = (float*)d_out;
    int E = in_sizes[1] / 2;

    char* ws = (char*)d_ws;
    unsigned int* adj = (unsigned int*)ws;                 // 2 MiB
    short* Bp     = (short*)(ws + (2u << 20));             // 64 KiB (packed bf16 W1)
    float* feats1 = (float*)(ws + (3u << 20));             // 1 MiB
    float* s1     = (float*)(ws + (4u << 20));             // 256 KiB
    float* feats2 = (float*)(ws + (5u << 20));             // 128 KiB
    float* s2     = (float*)(ws + (6u << 20));             // 32 KiB
    int*   deg    = (int*)  (ws + (7u << 20));             // 16 KiB
    int*   nbrL   = (int*)  (ws + (16u << 20));            // 64 MiB

    k_init   <<<2048, 256, 0, stream>>>(adj, deg, W1, Bp);
    k_scatter<<<(E + NNODES + 255) / 256, 256, 0, stream>>>(ei, E, adj, deg, nbrL);
    k_gemm   <<<NNODES / 16, 256, 0, stream>>>(x, Bp, b1, al1, ar1, feats1, s1);
    k_attn1  <<<NNODES / 4, 256, 0, stream>>>(nbrL, deg, feats1, s1, W2, b2, al2, ar2, feats2, s2);
    k_attn2  <<<NNODES / 4, 256, 0, stream>>>(nbrL, deg, feats2, s2, out);
}

// Round 6
// 108.117 us; speedup vs baseline: 3.1875x; 1.0222x over previous
//
#include <hip/hip_runtime.h>
#include <math.h>

#define NNODES 4096
#define FDIM 512
#define CHID 64
#define NHEAD 8
#define NCLS 7
#define MAXD 4096        // neighbor-list stride (clamped; far above max real degree)

typedef short bf16x8 __attribute__((ext_vector_type(8)));
typedef float f32x4  __attribute__((ext_vector_type(4)));

// round-to-nearest-even f32 -> bf16 (finite inputs only)
static __device__ inline short f2bf(float f) {
    union { float f; unsigned u; } v; v.f = f;
    unsigned r = v.u + 0x7fffu + ((v.u >> 16) & 1u);
    return (short)(r >> 16);
}

// ---------- K1: zero per-row degree counters (16 KB) ----------
__global__ void k_zero(int* __restrict__ deg) {
    deg[blockIdx.x * 256 + threadIdx.x] = 0;
}

// ---------- K2: layer-1 GEMM (blocks 0..255) + edge scatter (blocks 256..) ----------
// GEMM: block = 16 rows x 64 cols, wave w = K-quarter; B-fragments gathered from W1.
// Scatter: raw append (dup-tolerant), diagonal as t in [E, E+N).
__global__ void __launch_bounds__(256) k_main(const float* __restrict__ x, const float* __restrict__ W1,
                                              const float* __restrict__ b1, const float* __restrict__ al,
                                              const float* __restrict__ ar, const int* __restrict__ ei,
                                              int E, float* __restrict__ feats, float* __restrict__ s1,
                                              int* __restrict__ deg, int* __restrict__ nbrL) {
    if (blockIdx.x >= 256) {   // ---- scatter path ----
        const int t = (blockIdx.x - 256) * 256 + threadIdx.x;
        if (t < E + NNODES) {
            int r, c;
            if (t < E) { r = ei[t]; c = ei[E + t]; }
            else       { r = c = t - E; }              // self-loop / diagonal
            const int p = atomicAdd(&deg[r], 1);
            if (p < MAXD) nbrL[r * MAXD + p] = c;
        }
        return;
    }
    // ---- GEMM path ----
    __shared__ float red[4][4][64][4];   // [kq][cq][l][r] = 16 KB
    const int w = threadIdx.x >> 6, l = threadIdx.x & 63;
    const int row0 = blockIdx.x * 16;
    const int arow = row0 + (l & 15);
    const int koff = (l >> 4) * 8;
    f32x4 acc0 = {0,0,0,0}, acc1 = {0,0,0,0}, acc2 = {0,0,0,0}, acc3 = {0,0,0,0};
    #pragma unroll
    for (int q = 0; q < 4; ++q) {
        const int kb = w * 4 + q;
        const float* ap = &x[arow * FDIM + kb * 32 + koff];
        const float4 a0 = *(const float4*)ap;
        const float4 a1 = *(const float4*)(ap + 4);
        bf16x8 af = { f2bf(a0.x), f2bf(a0.y), f2bf(a0.z), f2bf(a0.w),
                      f2bf(a1.x), f2bf(a1.y), f2bf(a1.z), f2bf(a1.w) };
        const float* wp = &W1[(kb * 32 + (l >> 4) * 8) * 64 + (l & 15)];
        bf16x8 bf0, bf1, bf2, bf3;
        #pragma unroll
        for (int j = 0; j < 8; ++j) {
            bf0[j] = f2bf(wp[j * 64 + 0]);
            bf1[j] = f2bf(wp[j * 64 + 16]);
            bf2[j] = f2bf(wp[j * 64 + 32]);
            bf3[j] = f2bf(wp[j * 64 + 48]);
        }
        acc0 = __builtin_amdgcn_mfma_f32_16x16x32_bf16(af, bf0, acc0, 0, 0, 0);
        acc1 = __builtin_amdgcn_mfma_f32_16x16x32_bf16(af, bf1, acc1, 0, 0, 0);
        acc2 = __builtin_amdgcn_mfma_f32_16x16x32_bf16(af, bf2, acc2, 0, 0, 0);
        acc3 = __builtin_amdgcn_mfma_f32_16x16x32_bf16(af, bf3, acc3, 0, 0, 0);
    }
    #pragma unroll
    for (int r = 0; r < 4; ++r) {
        red[w][0][l][r] = acc0[r];
        red[w][1][l][r] = acc1[r];
        red[w][2][l][r] = acc2[r];
        red[w][3][l][r] = acc3[r];
    }
    __syncthreads();
    // thread (w,l) finalizes col = w*16+(l&15), rows r0..r0+3 (sums over K-quarters)
    const int col = w * 16 + (l & 15);
    const int r0 = row0 + (l >> 4) * 4;
    const float bias = b1[col];
    const int c = col & 7, h = col >> 3;
    const float vl = al[c * NHEAD + h];   // a_left1[c][h]
    const float vr = ar[c * NHEAD + h];
    #pragma unroll
    for (int r = 0; r < 4; ++r) {
        float fv = red[0][w][l][r] + red[1][w][l][r] + red[2][w][l][r] + red[3][w][l][r] + bias;
        feats[(r0 + r) * CHID + col] = fv;
        float ps = fv * vl, pt = fv * vr;
        ps += __shfl_xor(ps, 1); ps += __shfl_xor(ps, 2); ps += __shfl_xor(ps, 4);
        pt += __shfl_xor(pt, 1); pt += __shfl_xor(pt, 2); pt += __shfl_xor(pt, 4);
        if ((l & 7) == 0) {
            s1[(r0 + r) * 16 + h] = ps;
            s1[(r0 + r) * 16 + 8 + h] = pt;
        }
    }
}

// ---------- K3: layer-1 sparse attention (ballot dedup) + ELU + layer-2 proj & scores ----------
// 1024 blocks x 256 threads; wave w -> node i = blockIdx*4 + w; lane l = h*8+c
__global__ void __launch_bounds__(256) k_attn1(const int* __restrict__ nbrL, const int* __restrict__ deg,
                                               const float* __restrict__ feats,
                                               const float* __restrict__ s1,
                                               const float* __restrict__ W2,
                                               const float* __restrict__ b2,
                                               const float* __restrict__ al2,
                                               const float* __restrict__ ar2,
                                               float* __restrict__ feats2,
                                               float* __restrict__ s2) {
    const int w = threadIdx.x >> 6, l = threadIdx.x & 63;
    const int i = blockIdx.x * 4 + w;
    const int h = l >> 3;
    int nn = deg[i]; if (nn > MAXD) nn = MAXD;
    const float stgt = s1[i * 16 + 8 + h];
    float den = 0.f, acc = 0.f;
    if (nn <= 64) {
        const int jv = (l < nn) ? nbrL[i * MAXD + l] : (0x40000000 + l);  // sentinel: never matches
        for (int k = 0; k < nn; ++k) {
            const int j = __shfl(jv, k);
            const unsigned long long eq = __ballot(jv == j);
            if (eq & ((1ULL << k) - 1ULL)) continue;     // duplicate of earlier entry
            float sc = s1[j * 16 + h] + stgt;
            sc = sc > 0.f ? sc : 0.2f * sc;
            const float p = __expf(sc);                  // |scores| small: no max pass needed
            den += p;
            acc = fmaf(p, feats[j * CHID + l], acc);
        }
    } else {   // rare fallback: quadratic dedup, correctness-only path
        const int base = i * MAXD;
        for (int k = 0; k < nn; ++k) {
            const int j = nbrL[base + k];
            bool d = false;
            for (int kk = l; kk < k; kk += 64) d |= (nbrL[base + kk] == j);
            if (__any(d)) continue;
            float sc = s1[j * 16 + h] + stgt;
            sc = sc > 0.f ? sc : 0.2f * sc;
            const float p = __expf(sc);
            den += p;
            acc = fmaf(p, feats[j * CHID + l], acc);
        }
    }
    const float o = acc / den;
    const float h1v = o > 0.f ? o : (__expf(o) - 1.f);   // ELU
    float t7[NCLS];
    #pragma unroll
    for (int c2 = 0; c2 < NCLS; ++c2) {
        float p = h1v * W2[l * NCLS + c2];
        p += __shfl_xor(p, 1);  p += __shfl_xor(p, 2);  p += __shfl_xor(p, 4);
        p += __shfl_xor(p, 8);  p += __shfl_xor(p, 16); p += __shfl_xor(p, 32);
        t7[c2] = p + b2[c2];
    }
    if (l == 0) {
        float ss = 0.f, st = 0.f;
        #pragma unroll
        for (int c2 = 0; c2 < NCLS; ++c2) {
            ss = fmaf(t7[c2], al2[c2], ss);
            st = fmaf(t7[c2], ar2[c2], st);
        }
        #pragma unroll
        for (int c2 = 0; c2 < NCLS; ++c2) feats2[i * 8 + c2] = t7[c2];
        feats2[i * 8 + 7] = 0.f;
        s2[i * 2] = ss;
        s2[i * 2 + 1] = st;
    }
}

// ---------- K4: layer-2 sparse attention (ballot dedup) -> output [4096,7] f32 ----------
__global__ void __launch_bounds__(256) k_attn2(const int* __restrict__ nbrL, const int* __restrict__ deg,
                                               const float* __restrict__ feats2,
                                               const float* __restrict__ s2,
                                               float* __restrict__ out) {
    const int w = threadIdx.x >> 6, l = threadIdx.x & 63;
    const int i = blockIdx.x * 4 + w;
    int nn = deg[i]; if (nn > MAXD) nn = MAXD;
    const int c = l & 7;
    const float stgt = s2[i * 2 + 1];
    float den = 0.f, acc = 0.f;
    if (nn <= 64) {
        const int jv = (l < nn) ? nbrL[i * MAXD + l] : (0x40000000 + l);
        for (int k = 0; k < nn; ++k) {
            const int j = __shfl(jv, k);
            const unsigned long long eq = __ballot(jv == j);
            if (eq & ((1ULL << k) - 1ULL)) continue;
            float sc = s2[j * 2] + stgt;
            sc = sc > 0.f ? sc : 0.2f * sc;
            const float p = __expf(sc);
            den += p;
            acc = fmaf(p, feats2[j * 8 + c], acc);
        }
    } else {
        const int base = i * MAXD;
        for (int k = 0; k < nn; ++k) {
            const int j = nbrL[base + k];
            bool d = false;
            for (int kk = l; kk < k; kk += 64) d |= (nbrL[base + kk] == j);
            if (__any(d)) continue;
            float sc = s2[j * 2] + stgt;
            sc = sc > 0.f ? sc : 0.2f * sc;
            const float p = __expf(sc);
            den += p;
            acc = fmaf(p, feats2[j * 8 + c], acc);
        }
    }
    if (l < NCLS) out[i * NCLS + l] = acc / den;
}

extern "C" void kernel_launch(void* const* d_in, const int* in_sizes, int n_in,
                              void* d_out, int out_size, void* d_ws, size_t ws_size,
                              hipStream_t stream) {
    const float* x   = (const float*)d_in[0];
    const int*   ei  = (const int*)d_in[1];
    const float* W1  = (const float*)d_in[2];
    const float* b1  = (const float*)d_in[3];
    const float* al1 = (const float*)d_in[4];
    const float* ar1 = (const float*)d_in[5];
    const float* W2  = (const float*)d_in[6];
    const float* b2  = (const float*)d_in[7];
    const float* al2 = (const float*)d_in[8];
    const float* ar2 = (const float*)d_in[9];
    float* out = (float*)d_out;
    int E = in_sizes[1] / 2;

    char* ws = (char*)d_ws;
    float* feats1 = (float*)(ws);                          // 1 MiB
    float* s1     = (float*)(ws + (1u << 20));             // 256 KiB
    float* feats2 = (float*)(ws + (2u << 20));             // 128 KiB
    float* s2     = (float*)(ws + (3u << 20));             // 32 KiB
    int*   deg    = (int*)  (ws + (4u << 20));             // 16 KiB
    int*   nbrL   = (int*)  (ws + (8u << 20));             // 64 MiB

    const int scat_blocks = (E + NNODES + 255) / 256;
    k_zero   <<<NNODES / 256, 256, 0, stream>>>(deg);
    k_main   <<<256 + scat_blocks, 256, 0, stream>>>(x, W1, b1, al1, ar1, ei, E, feats1, s1, deg, nbrL);
    k_attn1  <<<NNODES / 4, 256, 0, stream>>>(nbrL, deg, feats1, s1, W2, b2, al2, ar2, feats2, s2);
    k_attn2  <<<NNODES / 4, 256, 0, stream>>>(nbrL, deg, feats2, s2, out);
}

// Round 7
// 108.089 us; speedup vs baseline: 3.1883x; 1.0003x over previous
//
#include <hip/hip_runtime.h>
#include <math.h>

#define NNODES 4096
#define FDIM 512
#define CHID 64
#define NHEAD 8
#define NCLS 7
#define MAXD 4096        // neighbor-list stride (clamped; far above max real degree)

typedef short bf16x8 __attribute__((ext_vector_type(8)));
typedef float f32x4  __attribute__((ext_vector_type(4)));

// round-to-nearest-even f32 -> bf16 (finite inputs only)
static __device__ inline short f2bf(float f) {
    union { float f; unsigned u; } v; v.f = f;
    unsigned r = v.u + 0x7fffu + ((v.u >> 16) & 1u);
    return (short)(r >> 16);
}

// ---------- K1: layer-1 GEMM (blocks 0..255) + edge scatter (blocks 256..) ----------
// GEMM: block = 16 rows x 64 cols, 512 threads; wave w = K-eighth (2 kb iters).
// Scatter: raw append (dup-tolerant), diagonal as t in [E, E+N).
__global__ void __launch_bounds__(512) k_main(const float* __restrict__ x, const float* __restrict__ W1,
                                              const float* __restrict__ b1, const float* __restrict__ al,
                                              const float* __restrict__ ar, const int* __restrict__ ei,
                                              int E, float* __restrict__ feats, float* __restrict__ s1,
                                              int* __restrict__ deg, int* __restrict__ nbrL) {
    if (blockIdx.x >= 256) {   // ---- scatter path ----
        const int t = (blockIdx.x - 256) * 512 + threadIdx.x;
        if (t < E + NNODES) {
            int r, c;
            if (t < E) { r = ei[t]; c = ei[E + t]; }
            else       { r = c = t - E; }              // self-loop / diagonal
            const int p = atomicAdd(&deg[r], 1);
            if (p < MAXD) nbrL[r * MAXD + p] = c;
        }
        return;
    }
    // ---- GEMM path ----
    __shared__ float red[8][4][64][4];   // [kw][cq][l][r] = 32 KB
    const int w = threadIdx.x >> 6, l = threadIdx.x & 63;
    const int row0 = blockIdx.x * 16;
    const int arow = row0 + (l & 15);
    const int koff = (l >> 4) * 8;
    f32x4 acc0 = {0,0,0,0}, acc1 = {0,0,0,0}, acc2 = {0,0,0,0}, acc3 = {0,0,0,0};
    #pragma unroll
    for (int q = 0; q < 2; ++q) {
        const int kb = w * 2 + q;
        const float* ap = &x[arow * FDIM + kb * 32 + koff];
        const float4 a0 = *(const float4*)ap;
        const float4 a1 = *(const float4*)(ap + 4);
        bf16x8 af = { f2bf(a0.x), f2bf(a0.y), f2bf(a0.z), f2bf(a0.w),
                      f2bf(a1.x), f2bf(a1.y), f2bf(a1.z), f2bf(a1.w) };
        const float* wp = &W1[(kb * 32 + (l >> 4) * 8) * 64 + (l & 15)];
        bf16x8 bf0, bf1, bf2, bf3;
        #pragma unroll
        for (int j = 0; j < 8; ++j) {
            bf0[j] = f2bf(wp[j * 64 + 0]);
            bf1[j] = f2bf(wp[j * 64 + 16]);
            bf2[j] = f2bf(wp[j * 64 + 32]);
            bf3[j] = f2bf(wp[j * 64 + 48]);
        }
        acc0 = __builtin_amdgcn_mfma_f32_16x16x32_bf16(af, bf0, acc0, 0, 0, 0);
        acc1 = __builtin_amdgcn_mfma_f32_16x16x32_bf16(af, bf1, acc1, 0, 0, 0);
        acc2 = __builtin_amdgcn_mfma_f32_16x16x32_bf16(af, bf2, acc2, 0, 0, 0);
        acc3 = __builtin_amdgcn_mfma_f32_16x16x32_bf16(af, bf3, acc3, 0, 0, 0);
    }
    #pragma unroll
    for (int r = 0; r < 4; ++r) {
        red[w][0][l][r] = acc0[r];
        red[w][1][l][r] = acc1[r];
        red[w][2][l][r] = acc2[r];
        red[w][3][l][r] = acc3[r];
    }
    __syncthreads();
    // epilogue: thread (w,l) -> col = (w&3)*16 + (l&15), rows r0 + {0,1} (w<4) / {2,3} (w>=4)
    const int cq = w & 3;
    const int col = cq * 16 + (l & 15);
    const int r0 = row0 + (l >> 4) * 4;
    const int rlo = (w >> 2) * 2;
    const float bias = b1[col];
    const int c = col & 7, h = col >> 3;
    const float vl = al[c * NHEAD + h];   // a_left1[c][h]
    const float vr = ar[c * NHEAD + h];
    #pragma unroll
    for (int rr = 0; rr < 2; ++rr) {
        const int r = rlo + rr;
        float fv = bias;
        #pragma unroll
        for (int kw = 0; kw < 8; ++kw) fv += red[kw][cq][l][r];
        feats[(r0 + r) * CHID + col] = fv;
        float ps = fv * vl, pt = fv * vr;
        ps += __shfl_xor(ps, 1); ps += __shfl_xor(ps, 2); ps += __shfl_xor(ps, 4);
        pt += __shfl_xor(pt, 1); pt += __shfl_xor(pt, 2); pt += __shfl_xor(pt, 4);
        if ((l & 7) == 0) {
            s1[(r0 + r) * 16 + h] = ps;
            s1[(r0 + r) * 16 + 8 + h] = pt;
        }
    }
}

// ---------- K2: layer-1 sparse attention (ballot dedup) + ELU + layer-2 proj & scores ----------
// 1024 blocks x 256 threads; wave w -> node i = blockIdx*4 + w; lane l = h*8+c
__global__ void __launch_bounds__(256) k_attn1(const int* __restrict__ nbrL, const int* __restrict__ deg,
                                               const float* __restrict__ feats,
                                               const float* __restrict__ s1,
                                               const float* __restrict__ W2,
                                               const float* __restrict__ b2,
                                               const float* __restrict__ al2,
                                               const float* __restrict__ ar2,
                                               float* __restrict__ feats2,
                                               float* __restrict__ s2) {
    const int w = threadIdx.x >> 6, l = threadIdx.x & 63;
    const int i = blockIdx.x * 4 + w;
    const int h = l >> 3;
    int nn = deg[i]; if (nn > MAXD) nn = MAXD;
    const float stgt = s1[i * 16 + 8 + h];
    float den = 0.f, acc = 0.f;
    if (nn <= 64) {
        const int jv = (l < nn) ? nbrL[i * MAXD + l] : (0x40000000 + l);  // sentinel: never matches
        for (int k = 0; k < nn; ++k) {
            const int j = __shfl(jv, k);
            const unsigned long long eq = __ballot(jv == j);
            if (eq & ((1ULL << k) - 1ULL)) continue;     // duplicate of earlier entry
            float sc = s1[j * 16 + h] + stgt;
            sc = sc > 0.f ? sc : 0.2f * sc;
            const float p = __expf(sc);                  // |scores| small: no max pass needed
            den += p;
            acc = fmaf(p, feats[j * CHID + l], acc);
        }
    } else {   // rare fallback: quadratic dedup, correctness-only path
        const int base = i * MAXD;
        for (int k = 0; k < nn; ++k) {
            const int j = nbrL[base + k];
            bool d = false;
            for (int kk = l; kk < k; kk += 64) d |= (nbrL[base + kk] == j);
            if (__any(d)) continue;
            float sc = s1[j * 16 + h] + stgt;
            sc = sc > 0.f ? sc : 0.2f * sc;
            const float p = __expf(sc);
            den += p;
            acc = fmaf(p, feats[j * CHID + l], acc);
        }
    }
    const float o = acc / den;
    const float h1v = o > 0.f ? o : (__expf(o) - 1.f);   // ELU
    float t7[NCLS];
    #pragma unroll
    for (int c2 = 0; c2 < NCLS; ++c2) {
        float p = h1v * W2[l * NCLS + c2];
        p += __shfl_xor(p, 1);  p += __shfl_xor(p, 2);  p += __shfl_xor(p, 4);
        p += __shfl_xor(p, 8);  p += __shfl_xor(p, 16); p += __shfl_xor(p, 32);
        t7[c2] = p + b2[c2];
    }
    if (l == 0) {
        float ss = 0.f, st = 0.f;
        #pragma unroll
        for (int c2 = 0; c2 < NCLS; ++c2) {
            ss = fmaf(t7[c2], al2[c2], ss);
            st = fmaf(t7[c2], ar2[c2], st);
        }
        #pragma unroll
        for (int c2 = 0; c2 < NCLS; ++c2) feats2[i * 8 + c2] = t7[c2];
        feats2[i * 8 + 7] = 0.f;
        s2[i * 2] = ss;
        s2[i * 2 + 1] = st;
    }
}

// ---------- K3: layer-2 sparse attention (ballot dedup) -> output [4096,7] f32 ----------
__global__ void __launch_bounds__(256) k_attn2(const int* __restrict__ nbrL, const int* __restrict__ deg,
                                               const float* __restrict__ feats2,
                                               const float* __restrict__ s2,
                                               float* __restrict__ out) {
    const int w = threadIdx.x >> 6, l = threadIdx.x & 63;
    const int i = blockIdx.x * 4 + w;
    int nn = deg[i]; if (nn > MAXD) nn = MAXD;
    const int c = l & 7;
    const float stgt = s2[i * 2 + 1];
    float den = 0.f, acc = 0.f;
    if (nn <= 64) {
        const int jv = (l < nn) ? nbrL[i * MAXD + l] : (0x40000000 + l);
        for (int k = 0; k < nn; ++k) {
            const int j = __shfl(jv, k);
            const unsigned long long eq = __ballot(jv == j);
            if (eq & ((1ULL << k) - 1ULL)) continue;
            float sc = s2[j * 2] + stgt;
            sc = sc > 0.f ? sc : 0.2f * sc;
            const float p = __expf(sc);
            den += p;
            acc = fmaf(p, feats2[j * 8 + c], acc);
        }
    } else {
        const int base = i * MAXD;
        for (int k = 0; k < nn; ++k) {
            const int j = nbrL[base + k];
            bool d = false;
            for (int kk = l; kk < k; kk += 64) d |= (nbrL[base + kk] == j);
            if (__any(d)) continue;
            float sc = s2[j * 2] + stgt;
            sc = sc > 0.f ? sc : 0.2f * sc;
            const float p = __expf(sc);
            den += p;
            acc = fmaf(p, feats2[j * 8 + c], acc);
        }
    }
    if (l < NCLS) out[i * NCLS + l] = acc / den;
}

extern "C" void kernel_launch(void* const* d_in, const int* in_sizes, int n_in,
                              void* d_out, int out_size, void* d_ws, size_t ws_size,
                              hipStream_t stream) {
    const float* x   = (const float*)d_in[0];
    const int*   ei  = (const int*)d_in[1];
    const float* W1  = (const float*)d_in[2];
    const float* b1  = (const float*)d_in[3];
    const float* al1 = (const float*)d_in[4];
    const float* ar1 = (const float*)d_in[5];
    const float* W2  = (const float*)d_in[6];
    const float* b2  = (const float*)d_in[7];
    const float* al2 = (const float*)d_in[8];
    const float* ar2 = (const float*)d_in[9];
    float* out = (float*)d_out;
    int E = in_sizes[1] / 2;

    char* ws = (char*)d_ws;
    float* feats1 = (float*)(ws);                          // 1 MiB
    float* s1     = (float*)(ws + (1u << 20));             // 256 KiB
    float* feats2 = (float*)(ws + (2u << 20));             // 128 KiB
    float* s2     = (float*)(ws + (3u << 20));             // 32 KiB
    int*   deg    = (int*)  (ws + (4u << 20));             // 16 KiB
    int*   nbrL   = (int*)  (ws + (8u << 20));             // 64 MiB

    hipMemsetAsync(deg, 0, NNODES * sizeof(int), stream);
    const int scat_blocks = (E + NNODES + 511) / 512;
    k_main   <<<256 + scat_blocks, 512, 0, stream>>>(x, W1, b1, al1, ar1, ei, E, feats1, s1, deg, nbrL);
    k_attn1  <<<NNODES / 4, 256, 0, stream>>>(nbrL, deg, feats1, s1, W2, b2, al2, ar2, feats2, s2);
    k_attn2  <<<NNODES / 4, 256, 0, stream>>>(nbrL, deg, feats2, s2, out);
}